// Round 2
// baseline (1819.116 us; speedup 1.0000x reference)
//
#include <hip/hip_runtime.h>
#include <cstdint>

namespace {

constexpr int kB   = 32;          // batches
constexpr int kN   = 131072;      // points per batch
constexpr int kC   = 6;           // channels
constexpr int TPB  = 256;         // threads per block (1 point / thread)
constexpr int BPB  = kN / TPB;    // 512 blocks per batch
constexpr int NBLK = kB * BPB;    // 16384 blocks total

constexpr uint32_t FLAG_AGG = 1u << 30;
constexpr uint32_t FLAG_PRE = 2u << 30;
constexpr uint32_t VAL_MASK = (1u << 30) - 1u;

__device__ __forceinline__ int waveSum(int v) {
#pragma unroll
    for (int off = 32; off; off >>= 1) v += __shfl_xor(v, off, 64);
    return v;
}

__global__ __launch_bounds__(256) void k_init(uint32_t* __restrict__ ws, int n) {
    int i = blockIdx.x * 256 + threadIdx.x;
    if (i < n) ws[i] = 0u;
}

__global__ __launch_bounds__(TPB) void k_fused(const float* __restrict__ pc,
                                               const float* __restrict__ tt,
                                               float* __restrict__ out,
                                               uint32_t* __restrict__ ticket,
                                               uint32_t* __restrict__ totals,
                                               uint32_t* __restrict__ flags) {
    __shared__ int s_vb;
    __shared__ int s_excl;
    __shared__ int s_total;
    __shared__ int wc[4];

    const int tid = threadIdx.x;
    if (tid == 0) s_vb = (int)atomicAdd(ticket, 1u);
    __syncthreads();
    const int vb   = s_vb;              // virtual block id, in dispatch order
    const int b    = vb >> 9;           // vb / 512
    const int k    = vb & (BPB - 1);    // block index within batch
    const int n    = k * TPB + tid;     // point index within batch
    const int lane = tid & 63;
    const int wv   = tid >> 6;

    // ---- load row + validity (exact same arithmetic as reference) ----
    const float* T = tt + b * 16;       // 4x4 row-major
    const float2* row = (const float2*)(pc + ((size_t)b * kN + n) * kC);
    float2 a0 = row[0];                 // x, y
    float2 a1 = row[1];                 // z, nx
    float2 a2 = row[2];                 // ny, nz
    const float x = a0.x, y = a0.y, z = a1.x;
    const float nsum = (a1.y + a2.x) + a2.y;
    const float px = x * T[0] + y * T[4] + z * T[8]  + T[3];
    const float py = x * T[1] + y * T[5] + z * T[9]  + T[7];
    const float pz = x * T[2] + y * T[6] + z * T[10] + T[11];
    const bool valid = (px * px + py * py < 1.0f) && (pz < 1.0f) && (nsum != 0.0f);

    const uint64_t m = __ballot(valid);
    if (lane == 0) wc[wv] = __popcll(m);
    __syncthreads();
    const int agg = wc[0] + wc[1] + wc[2] + wc[3];

    // ---- publish aggregate (or prefix, if first block of batch) ----
    if (tid == 0) {
        uint32_t word = (k == 0 ? FLAG_PRE : FLAG_AGG) | (uint32_t)agg;
        __hip_atomic_store(&flags[vb], word, __ATOMIC_RELEASE, __HIP_MEMORY_SCOPE_AGENT);
        if (k == 0) s_excl = 0;
    }

    // ---- decoupled lookback (wave 0, 64-wide window) ----
    if (k > 0 && wv == 0) {
        int excl = 0;
        int j = vb - 1;
        const int batchStart = b << 9;
        for (;;) {
            const int idx = j - lane;
            uint32_t w = 0;
            if (idx >= batchStart)
                w = __hip_atomic_load(&flags[idx], __ATOMIC_ACQUIRE, __HIP_MEMORY_SCOPE_AGENT);
            const uint64_t vmask = __ballot(w != 0u);
            const uint64_t inval = ~vmask;
            const int firstInvalid = inval ? (int)(__ffsll((long long)inval) - 1) : 64;
            uint64_t pmask = __ballot((w & FLAG_PRE) != 0u);
            if (firstInvalid < 64) pmask &= ((1ull << firstInvalid) - 1ull);
            if (pmask) {
                const int L = (int)(__ffsll((long long)pmask) - 1);
                const int v = (lane <= L) ? (int)(w & VAL_MASK) : 0;
                excl += waveSum(v);
                break;
            }
            const int cnt = firstInvalid;
            if (cnt > 0) {
                const int v = (lane < cnt) ? (int)(w & VAL_MASK) : 0;
                excl += waveSum(v);
                j -= cnt;
            } else {
                __builtin_amdgcn_s_sleep(1);
            }
        }
        if (lane == 0) s_excl = excl;
    }
    __syncthreads();
    const int excl = s_excl;
    const int inclusive = excl + agg;

    if (tid == 0) {
        if (k > 0)
            __hip_atomic_store(&flags[vb], FLAG_PRE | (uint32_t)inclusive,
                               __ATOMIC_RELEASE, __HIP_MEMORY_SCOPE_AGENT);
        if (k == BPB - 1)
            __hip_atomic_store(&totals[b], 0x80000000u | (uint32_t)inclusive,
                               __ATOMIC_RELEASE, __HIP_MEMORY_SCOPE_AGENT);
    }

    // ---- scatter valid rows (compacted, original order) ----
    int waveBase = 0;
#pragma unroll
    for (int w2 = 0; w2 < 3; ++w2)
        if (w2 < wv) waveBase += wc[w2];
    const int before = __popcll(m & ((1ull << lane) - 1ull));
    const int vcnt = excl + waveBase + before;   // valid strictly before point n
    const size_t outB = (size_t)b * kN;

    if (valid) {
        float2* o = (float2*)(out + (outB + (size_t)vcnt) * kC);
        o[0] = a0; o[1] = a1; o[2] = a2;
    }

    // ---- wait for batch total, then zero-fill tail slots ----
    if (tid == 0) {
        uint32_t tw;
        for (;;) {
            tw = __hip_atomic_load(&totals[b], __ATOMIC_ACQUIRE, __HIP_MEMORY_SCOPE_AGENT);
            if (tw & 0x80000000u) break;
            __builtin_amdgcn_s_sleep(2);
        }
        s_total = (int)(tw & 0x7FFFFFFFu);
    }
    __syncthreads();

    if (!valid) {
        const int dst = s_total + (n - vcnt);    // total + invalid-rank
        float2* o = (float2*)(out + (outB + (size_t)dst) * kC);
        const float2 zz = make_float2(0.0f, 0.0f);
        o[0] = zz; o[1] = zz; o[2] = zz;
    }
}

} // namespace

extern "C" void kernel_launch(void* const* d_in, const int* in_sizes, int n_in,
                              void* d_out, int out_size, void* d_ws, size_t ws_size,
                              hipStream_t stream) {
    const float* pc = (const float*)d_in[0];   // (32, 131072, 6) f32
    const float* tt = (const float*)d_in[1];   // (32, 4, 4) f32
    float* out = (float*)d_out;                // (32, 131072, 6) f32

    // ws layout: [0] ticket | [1..32] totals | [33..33+NBLK) flags
    uint32_t* ws      = (uint32_t*)d_ws;
    uint32_t* ticket  = ws;
    uint32_t* totals  = ws + 1;
    uint32_t* flags   = ws + 1 + kB;
    const int initN   = 1 + kB + NBLK;

    k_init<<<(initN + 255) / 256, 256, 0, stream>>>(ws, initN);
    k_fused<<<NBLK, TPB, 0, stream>>>(pc, tt, out, ticket, totals, flags);
}

// Round 3
// 47.330 us; speedup vs baseline: 38.4344x; 38.4344x over previous
//
#include <hip/hip_runtime.h>
#include <cstdint>

namespace {

constexpr int kB   = 32;          // batches
constexpr int kN   = 131072;      // points per batch
constexpr int kC   = 6;           // channels
constexpr int TPB  = 256;         // threads per block (1 point / thread)
constexpr int BPB  = kN / TPB;    // 512 blocks per batch
constexpr int NBLK = kB * BPB;    // 16384 blocks total
constexpr int WAVES = TPB / 64;   // 4 waves per block

__device__ __forceinline__ int waveSum(int v) {
#pragma unroll
    for (int off = 32; off; off >>= 1) v += __shfl_xor(v, off, 64);
    return v;
}

// Pass 1: per-block valid count + per-wave 64-bit validity masks.
// Rows staged through LDS so global reads are aligned float4 (16 B/lane).
__global__ __launch_bounds__(TPB) void k_count(const float* __restrict__ pc,
                                               const float* __restrict__ tt,
                                               uint64_t* __restrict__ masks,
                                               int* __restrict__ blkCnt) {
    const int blk = blockIdx.x;
    const int b   = blk >> 9;           // blk / BPB
    const int k   = blk & (BPB - 1);
    const int tid = threadIdx.x;
    const int lane = tid & 63;
    const int wv   = tid >> 6;

    __shared__ float4 sbuf[384];        // 256 rows * 24 B = 6144 B
    const float4* src = (const float4*)(pc + ((size_t)b * kN + (size_t)k * TPB) * kC);
    sbuf[tid] = src[tid];
    if (tid < 128) sbuf[256 + tid] = src[256 + tid];
    __syncthreads();

    const float* r = (const float*)sbuf + tid * 6;
    const float x = r[0], y = r[1], z = r[2];
    const float nsum = (r[3] + r[4]) + r[5];

    const float* T = tt + b * 16;       // 4x4 row-major
    const float px = x * T[0] + y * T[4] + z * T[8]  + T[3];
    const float py = x * T[1] + y * T[5] + z * T[9]  + T[7];
    const float pz = x * T[2] + y * T[6] + z * T[10] + T[11];
    const bool valid = (px * px + py * py < 1.0f) && (pz < 1.0f) && (nsum != 0.0f);

    const uint64_t m = __ballot(valid);
    __shared__ int wc[WAVES];
    if (lane == 0) {
        masks[(size_t)blk * WAVES + wv] = m;
        wc[wv] = __popcll(m);
    }
    __syncthreads();
    if (tid == 0) blkCnt[blk] = wc[0] + wc[1] + wc[2] + wc[3];
}

// Pass 2: scatter. Per-block prefix/total via a 512-count reduction (L2-hot).
// Valid rows -> compacted front (original order); invalid slots -> zeros.
__global__ __launch_bounds__(TPB) void k_scatter(const float* __restrict__ pc,
                                                 const uint64_t* __restrict__ masks,
                                                 const int* __restrict__ blkCnt,
                                                 float* __restrict__ out) {
    const int blk = blockIdx.x;
    const int b   = blk >> 9;
    const int k   = blk & (BPB - 1);
    const int tid = threadIdx.x;
    const int n   = k * TPB + tid;      // point index within batch
    const int lane = tid & 63;
    const int wv   = tid >> 6;

    __shared__ int wc[WAVES];
    __shared__ int pw[WAVES], tw[WAVES];

    const uint64_t m = masks[(size_t)blk * WAVES + wv];
    const bool valid = (m >> lane) & 1ull;
    if (lane == 0) wc[wv] = __popcll(m);

    // prefix = sum counts[i<k]; total = sum counts[all] (512 counts, 2/thread)
    const int* cnt = blkCnt + b * BPB;
    const int c0 = cnt[tid];
    const int c1 = cnt[tid + 256];
    int myPref = (tid < k ? c0 : 0) + (tid + 256 < k ? c1 : 0);
    int myTot  = c0 + c1;
    const int prefW = waveSum(myPref);
    const int totW  = waveSum(myTot);
    if (lane == 0) { pw[wv] = prefW; tw[wv] = totW; }
    __syncthreads();
    const int prefix = (pw[0] + pw[1]) + (pw[2] + pw[3]);
    const int total  = (tw[0] + tw[1]) + (tw[2] + tw[3]);

    int waveBase = 0;
#pragma unroll
    for (int w = 0; w < WAVES - 1; ++w)
        if (w < wv) waveBase += wc[w];
    const int before = __popcll(m & ((1ull << lane) - 1ull));
    const int vcnt   = prefix + waveBase + before;   // valid strictly before n
    const size_t outB = (size_t)b * kN;

    if (valid) {
        const float2* row = (const float2*)(pc + (outB + (size_t)n) * kC);
        const float2 a0 = row[0], a1 = row[1], a2 = row[2];
        float2* o = (float2*)(out + (outB + (size_t)vcnt) * kC);
        o[0] = a0; o[1] = a1; o[2] = a2;
    } else {
        const int dst = total + (n - vcnt);          // total + invalid-rank
        float2* o = (float2*)(out + (outB + (size_t)dst) * kC);
        const float2 zz = make_float2(0.0f, 0.0f);
        o[0] = zz; o[1] = zz; o[2] = zz;
    }
}

} // namespace

extern "C" void kernel_launch(void* const* d_in, const int* in_sizes, int n_in,
                              void* d_out, int out_size, void* d_ws, size_t ws_size,
                              hipStream_t stream) {
    const float* pc = (const float*)d_in[0];   // (32, 131072, 6) f32
    const float* tt = (const float*)d_in[1];   // (32, 4, 4) f32
    float* out = (float*)d_out;                // (32, 131072, 6) f32

    // ws layout: blkCnt (NBLK ints, 64 KiB) | masks (NBLK*4 u64, 512 KiB)
    int* blkCnt      = (int*)d_ws;
    uint64_t* masks  = (uint64_t*)((char*)d_ws + (size_t)NBLK * sizeof(int));

    k_count<<<NBLK, TPB, 0, stream>>>(pc, tt, masks, blkCnt);
    k_scatter<<<NBLK, TPB, 0, stream>>>(pc, masks, blkCnt, out);
}